// Round 15
// baseline (428.604 us; speedup 1.0000x reference)
//
#include <hip/hip_runtime.h>
#include <stdint.h>

// LiquidStateMachine on MI355X — round 15.
// r14 (310us) showed barrier/tail/step-start-L2 were NOT binding. Remaining
// gaps: (a) 8.8K cyc/step vs ~5K busiest-pipe floor -> gather/consume chain
// exposed at 2 waves/SIMD (2-deep pipeline too shallow); (b) ~73us
// prologue/epilogue overhead dominated by scattered 4B accesses through the
// perm indirection. r15:
//  (1) 3-deep gather + 3-deep streamed-weight pipeline (VGPR free at our
//      8-waves/CU occupancy; canary = WRITE_SIZE stays 12.3MB, no spill).
//  (2) cin/vin staged through LDS: coalesced global reads by q, LDS
//      redistribute by n.
//  (3) epilogue staged through LDS: coalesced out stores by q.
// Keeps: ping-pong spike buffers (1 barrier/step), SIMD balance, resident
// chunk-0..2 weights, full index-stream register preload.
// Weights EXACT fp32 (r2: rounding flips spikes); u8 spike 0/1 exact.
//
// d_ws layout (bytes):
//   0      PERM[512]  sorted-rank -> column
//   2048   RANK[512]  column -> sorted rank
//   4096   CNT[512]   nnz per column          (zeroed via hipMemsetAsync)
//   8192   CNTW[8]    per-group padded trip count (multiple of 8)
//   8256   IBASE[8]   per-group byte base into IDX region
//   8320   WBASE[8]   per-group byte base into WT region
//   16384  IDX        u16 spike-offset (8k):
//                     byte = ib + (j>>3)*1024 + lane*16 + (j&7)*2
//   81920  WT         f32 w: byte = wb + (j>>3)*2048 + lane*32 + (j&7)*4

#define N_NEU 512
#define B_ROWS 2048
#define D_IN 256
#define R_PB 8
#define NBLK (B_ROWS / R_PB)   // 256 blocks x 512 threads = 1 block/CU

#define WS_PERM    0
#define WS_RANK    2048
#define WS_CNT     4096
#define WS_CNTW    8192
#define WS_IBASE   8256
#define WS_WBASE   8320
#define WS_IDX     16384
#define WS_WT      81920

// spike record: 8 bytes (8 rows x u8 0/1) at natural offset 8k
#define SPK_OFF(k)  ((k) << 3)
#define SPK_BUF     4096       // one buffer: 512 neurons x 8 B

// ---------------------------------------------------------------- prep A
__global__ __launch_bounds__(256) void lsm_count(
    const float* __restrict__ W, uint32_t* __restrict__ ws)
{
    int t  = threadIdx.x;
    int k0 = blockIdx.x * 4;
    int c0 = 0, c1 = 0;
    #pragma unroll
    for (int kk = 0; kk < 4; ++kk) {
        const float* row = W + (size_t)(k0 + kk) * N_NEU;
        c0 += (row[t]       != 0.0f) ? 1 : 0;
        c1 += (row[t + 256] != 0.0f) ? 1 : 0;
    }
    if (c0) atomicAdd(&ws[(WS_CNT >> 2) + t],       (uint32_t)c0);
    if (c1) atomicAdd(&ws[(WS_CNT >> 2) + t + 256], (uint32_t)c1);
}

// ---------------------------------------------------------------- prep B
__global__ __launch_bounds__(512) void lsm_sort(uint32_t* __restrict__ ws)
{
    __shared__ int hist[N_NEU + 1];
    __shared__ int csort[N_NEU];
    __shared__ int gcw[8];

    int t = threadIdx.x;
    int creal = (int)ws[(WS_CNT >> 2) + t];
    for (int i = t; i < N_NEU + 1; i += 512) hist[i] = 0;
    __syncthreads();
    atomicAdd(&hist[creal], 1);
    __syncthreads();
    if (t == 0) {
        int acc = 0;
        for (int v = 0; v <= N_NEU; ++v) { int h = hist[v]; hist[v] = acc; acc += h; }
    }
    __syncthreads();
    int rank = atomicAdd(&hist[creal], 1);
    ws[(WS_PERM >> 2) + rank] = (uint32_t)t;
    ws[(WS_RANK >> 2) + t]    = (uint32_t)rank;
    csort[rank] = creal;
    __syncthreads();
    if (t < 8) {
        int cw = csort[t * 64 + 63];         // ascending -> group max is last
        cw = (cw + 7) & ~7;                  // pad to multiple of 8 (one chunk)
        gcw[t] = cw;
        ws[(WS_CNTW >> 2) + t] = (uint32_t)cw;
    }
    __syncthreads();
    if (t == 0) {
        int ai = 0, aw = 0;
        for (int g = 0; g < 8; ++g) {
            ws[(WS_IBASE >> 2) + g] = (uint32_t)ai;
            ws[(WS_WBASE >> 2) + g] = (uint32_t)aw;
            ai += gcw[g] * 64 * 2;           // bytes (u16 per entry)
            aw += gcw[g] * 64 * 4;           // bytes (f32 per entry)
        }
    }
    __syncthreads();
    // pad tail slots of this thread's column (offset 0 -> neuron 0, w=0)
    int wg = rank >> 6, ls = rank & 63;
    int cw = gcw[wg];
    uint32_t ib = ws[(WS_IBASE >> 2) + wg];
    uint32_t wb = ws[(WS_WBASE >> 2) + wg];
    char* base = (char*)ws;
    for (int j = creal; j < cw; ++j) {
        *(unsigned short*)(base + WS_IDX + ib + (j >> 3) * 1024 + ls * 16 + (j & 7) * 2) = 0;
        *(float*)(base + WS_WT + wb + (j >> 3) * 2048 + ls * 32 + (j & 7) * 4) = 0.0f;
    }
}

// ---------------------------------------------------------------- prep C
__global__ __launch_bounds__(64) void lsm_fill(
    const float* __restrict__ W, uint32_t* __restrict__ ws)
{
    int c    = blockIdx.x;
    int lane = threadIdx.x;
    char* base = (char*)ws;
    uint32_t rank = ws[(WS_RANK >> 2) + c];
    int wg = (int)(rank >> 6), ls = (int)(rank & 63);
    uint32_t ib = ws[(WS_IBASE >> 2) + wg];
    uint32_t wb = ws[(WS_WBASE >> 2) + wg];

    __shared__ int ctr;
    if (lane == 0) ctr = 0;
    __syncthreads();

    for (int k = lane; k < N_NEU; k += 64) {
        float wv = W[(size_t)k * N_NEU + c];
        if (wv != 0.0f) {
            int j = atomicAdd(&ctr, 1);      // order within column irrelevant
            *(unsigned short*)(base + WS_IDX + ib + (j >> 3) * 1024 + ls * 16 + (j & 7) * 2)
                = (unsigned short)SPK_OFF(k);
            *(float*)(base + WS_WT + wb + (j >> 3) * 2048 + ls * 32 + (j & 7) * 4) = wv;
        }
    }
}

// -------- spill-proof pipeline macros (all scalars, no arrays/fns) --------
// B = spike-buffer base for this step (smem + (t&1)*SPK_BUF)
#define GATH(P, X, B) \
    P##0 = *(const uint2*)((B) + ((X).x & 0xffffu)); \
    P##1 = *(const uint2*)((B) + ((X).x >> 16));     \
    P##2 = *(const uint2*)((B) + ((X).y & 0xffffu)); \
    P##3 = *(const uint2*)((B) + ((X).y >> 16));     \
    P##4 = *(const uint2*)((B) + ((X).z & 0xffffu)); \
    P##5 = *(const uint2*)((B) + ((X).z >> 16));     \
    P##6 = *(const uint2*)((B) + ((X).w & 0xffffu)); \
    P##7 = *(const uint2*)((B) + ((X).w >> 16));

// one entry: weight W x 8 rows' u8 spikes ((dw>>8j)&0xff -> v_cvt_f32_ubyteN)
#define C1(S, W) \
    rec0 = fmaf((W), (float)((S).x & 0xffu),         rec0); \
    rec1 = fmaf((W), (float)(((S).x >> 8) & 0xffu),  rec1); \
    rec2 = fmaf((W), (float)(((S).x >> 16) & 0xffu), rec2); \
    rec3 = fmaf((W), (float)((S).x >> 24),           rec3); \
    rec4 = fmaf((W), (float)((S).y & 0xffu),         rec4); \
    rec5 = fmaf((W), (float)(((S).y >> 8) & 0xffu),  rec5); \
    rec6 = fmaf((W), (float)(((S).y >> 16) & 0xffu), rec6); \
    rec7 = fmaf((W), (float)((S).y >> 24),           rec7);

#define CONS(P, WA, WB) \
    C1(P##0, (WA).x) C1(P##1, (WA).y) C1(P##2, (WA).z) C1(P##3, (WA).w) \
    C1(P##4, (WB).x) C1(P##5, (WB).y) C1(P##6, (WB).z) C1(P##7, (WB).w)

#define LDW(WA, WB, K) \
    WA = ((const float4*)(wp0 + (K) * 2048))[0]; \
    WB = ((const float4*)(wp0 + (K) * 2048))[1];

// ---------------------------------------------------------------- main
// LDS map:
//   [0,4096)       spk buffer 0 (u8 x 8 rows per neuron, 8B records @ 8k)
//   [4096,8192)    spk buffer 1 (ping-pong)
//   [8192,24576)   scratch 16KB: state staging -> rates rl -> out staging
__global__ __launch_bounds__(512, 1)
void lsm_main(
    const float* __restrict__ rates, const float* __restrict__ inW,
    const float* __restrict__ vin,   const float* __restrict__ cin,
    const int* __restrict__ nsteps_p,
    const uint32_t* __restrict__ ws, float* __restrict__ out)
{
    __shared__ __align__(16) unsigned char smem[2 * SPK_BUF + 16384];
    float* stg = (float*)(smem + 2 * SPK_BUF);   // 16KB scratch (4096 f32)
    float* rl  = stg;                            // rates overlay (8KB used)

    int q    = threadIdx.x;
    int blk  = blockIdx.x;
    int r0   = blk * R_PB;
    int w    = q >> 6;
    int lane = q & 63;
    // SIMD balance: waves {s, s+4} share SIMD s; give them groups {s, 7-s}
    int wg   = (w < 4) ? w : (11 - w);
    int n    = (int)ws[(WS_PERM >> 2) + wg * 64 + lane];
    int cw   = (int)ws[(WS_CNTW >> 2) + wg];     // wave-uniform
    int nit  = cw >> 3;                          // 8-entry chunks (<=12)
    const char* ip0 = (const char*)ws + WS_IDX + ws[(WS_IBASE >> 2) + wg]
                    + lane * 16;
    const char* wp0 = (const char*)ws + WS_WT  + ws[(WS_WBASE >> 2) + wg]
                    + lane * 32;
    int spk_n = SPK_OFF(n);                      // this column's record

    // ---- coalesced state staging: cin then vin through LDS ----
    float c0v[R_PB], v0v[R_PB], ssum[R_PB];
    #pragma unroll
    for (int r = 0; r < R_PB; ++r)
        stg[r * N_NEU + q] = cin[(size_t)(r0 + r) * N_NEU + q];   // coalesced
    __syncthreads();
    #pragma unroll
    for (int r = 0; r < R_PB; ++r) c0v[r] = stg[r * N_NEU + n];
    __syncthreads();
    #pragma unroll
    for (int r = 0; r < R_PB; ++r)
        stg[r * N_NEU + q] = vin[(size_t)(r0 + r) * N_NEU + q];   // coalesced
    __syncthreads();
    #pragma unroll
    for (int r = 0; r < R_PB; ++r) { v0v[r] = stg[r * N_NEU + n]; ssum[r] = 0.f; }
    __syncthreads();

    // ---- rates -> rl (coalesced), then I-dot ----
    ((float4*)rl)[q] = ((const float4*)(rates + (size_t)r0 * D_IN))[q];
    __syncthreads();

    float I[R_PB] = {0.f, 0.f, 0.f, 0.f, 0.f, 0.f, 0.f, 0.f};
    {
        const float4* wrow = (const float4*)(inW + (size_t)n * D_IN);
        for (int d4 = 0; d4 < D_IN / 4; ++d4) {
            float4 wv = wrow[d4];
            #pragma unroll
            for (int r = 0; r < R_PB; ++r) {
                const float* rr = rl + r * D_IN + d4 * 4;   // LDS broadcast
                I[r] += wv.x * rr[0] + wv.y * rr[1] + wv.z * rr[2] + wv.w * rr[3];
            }
        }
    }

    // initial u8 spikes -> buffer 0
    uint2 sini = make_uint2(0u, 0u);
    #pragma unroll
    for (int r = 0; r < R_PB; ++r) {
        unsigned bit = (c0v[r] > 0.f) ? 1u : 0u;
        if (r < 4) sini.x |= bit << (r * 8);
        else       sini.y |= bit << ((r - 4) * 8);
    }
    *(uint2*)(smem + spk_n) = sini;

    // preload ENTIRE index stream into registers (constant across steps)
    uint4 xr0, xr1, xr2, xr3, xr4, xr5, xr6, xr7, xr8, xr9, xr10, xr11;
    const uint4 xz = make_uint4(0u, 0u, 0u, 0u);
    xr0  =              *(const uint4*)(ip0);
    xr1  = (1  < nit) ? *(const uint4*)(ip0 + 1024)  : xz;
    xr2  = (2  < nit) ? *(const uint4*)(ip0 + 2048)  : xz;
    xr3  = (3  < nit) ? *(const uint4*)(ip0 + 3072)  : xz;
    xr4  = (4  < nit) ? *(const uint4*)(ip0 + 4096)  : xz;
    xr5  = (5  < nit) ? *(const uint4*)(ip0 + 5120)  : xz;
    xr6  = (6  < nit) ? *(const uint4*)(ip0 + 6144)  : xz;
    xr7  = (7  < nit) ? *(const uint4*)(ip0 + 7168)  : xz;
    xr8  = (8  < nit) ? *(const uint4*)(ip0 + 8192)  : xz;
    xr9  = (9  < nit) ? *(const uint4*)(ip0 + 9216)  : xz;
    xr10 = (10 < nit) ? *(const uint4*)(ip0 + 10240) : xz;
    xr11 = (11 < nit) ? *(const uint4*)(ip0 + 11264) : xz;

    // resident weights for chunks 0-2 (loop-invariant)
    float4 rw0a, rw0b, rw1a, rw1b, rw2a, rw2b;
    const float4 fz = make_float4(0.f, 0.f, 0.f, 0.f);
    rw0a = ((const float4*)wp0)[0];
    rw0b = ((const float4*)wp0)[1];
    rw1a = (1 < nit) ? ((const float4*)(wp0 + 2048))[0] : fz;
    rw1b = (1 < nit) ? ((const float4*)(wp0 + 2048))[1] : fz;
    rw2a = (2 < nit) ? ((const float4*)(wp0 + 4096))[0] : fz;
    rw2b = (2 < nit) ? ((const float4*)(wp0 + 4096))[1] : fz;

    const float AS   = (float)0.8187307530779818;   // exp(-1/5)
    const float OMAS = (float)(1.0 - 0.8187307530779818);
    const float AM   = (float)0.9512294245007140;   // exp(-1/20)
    const float OMAM = (float)(1.0 - 0.9512294245007140);

    int T = nsteps_p[0];
    __syncthreads();   // initial spikes visible

    #pragma unroll 1
    for (int t = 0; t < T; ++t) {
        const unsigned char* sb = smem + ((t & 1) ? SPK_BUF : 0);   // read buf
        unsigned char*       db = smem + ((t & 1) ? 0 : SPK_BUF);   // write buf

        float rec0 = 0.f, rec1 = 0.f, rec2 = 0.f, rec3 = 0.f;
        float rec4 = 0.f, rec5 = 0.f, rec6 = 0.f, rec7 = 0.f;
        uint2 ga0, ga1, ga2, ga3, ga4, ga5, ga6, ga7;
        uint2 gb0, gb1, gb2, gb3, gb4, gb5, gb6, gb7;
        uint2 gc0, gc1, gc2, gc3, gc4, gc5, gc6, gc7;
        float4 waA, wbA, waB, wbB, waC, wbC;

        // 3-deep pipeline: gathers for chunks 0-2 issue immediately
        // (addresses in registers), streamed weights 3 chunks ahead.
        GATH(ga, xr0, sb)
        if (1 < nit) { GATH(gb, xr1, sb) }
        if (2 < nit) { GATH(gc, xr2, sb) }
        if (3 < nit) { LDW(waA, wbA, 3) }
        if (4 < nit) { LDW(waB, wbB, 4) }
        if (5 < nit) { LDW(waC, wbC, 5) }

        // k=0..2: resident weights
        CONS(ga, rw0a, rw0b)
        if (3 < nit) { GATH(ga, xr3, sb) }
        if (1 < nit) {
            CONS(gb, rw1a, rw1b)
            if (4 < nit) { GATH(gb, xr4, sb) }
        }
        if (2 < nit) {
            CONS(gc, rw2a, rw2b)
            if (5 < nit) { GATH(gc, xr5, sb) }
        }
        // k=3.. : streamed weights, rotate {A,B,C}
        if (3 < nit) {
            CONS(ga, waA, wbA)
            if (6 < nit) { LDW(waA, wbA, 6) GATH(ga, xr6, sb) }
        }
        if (4 < nit) {
            CONS(gb, waB, wbB)
            if (7 < nit) { LDW(waB, wbB, 7) GATH(gb, xr7, sb) }
        }
        if (5 < nit) {
            CONS(gc, waC, wbC)
            if (8 < nit) { LDW(waC, wbC, 8) GATH(gc, xr8, sb) }
        }
        if (6 < nit) {
            CONS(ga, waA, wbA)
            if (9 < nit) { LDW(waA, wbA, 9) GATH(ga, xr9, sb) }
        }
        if (7 < nit) {
            CONS(gb, waB, wbB)
            if (10 < nit) { LDW(waB, wbB, 10) GATH(gb, xr10, sb) }
        }
        if (8 < nit) {
            CONS(gc, waC, wbC)
            if (11 < nit) { LDW(waC, wbC, 11) GATH(gc, xr11, sb) }
        }
        if (9 < nit)  { CONS(ga, waA, wbA) }
        if (10 < nit) { CONS(gb, waB, wbB) }
        if (11 < nit) { CONS(gc, waC, wbC) }

        // update + write new spikes to the other buffer (no WAR hazard)
        uint2 ns = make_uint2(0u, 0u);
        {
            float rca[R_PB] = {rec0, rec1, rec2, rec3, rec4, rec5, rec6, rec7};
            #pragma unroll
            for (int r = 0; r < R_PB; ++r) {
                c0v[r] = AS * c0v[r] + OMAS * (I[r] + rca[r]);
                v0v[r] = AM * v0v[r] + OMAM * c0v[r];
                ssum[r] += (v0v[r] > 0.f) ? 1.f : 0.f;
                unsigned bit = (c0v[r] > 0.f) ? 1u : 0u;
                if (r < 4) ns.x |= bit << (r * 8);
                else       ns.y |= bit << ((r - 4) * 8);
            }
        }
        *(uint2*)(db + spk_n) = ns;
        __syncthreads();   // new spikes visible; old buffer free for reuse
    }

    // ---- coalesced epilogue: stage each quantity through LDS ----
    float invT = 1.0f / (float)T;
    size_t BN = (size_t)B_ROWS * N_NEU;

    #pragma unroll
    for (int r = 0; r < R_PB; ++r) stg[r * N_NEU + n] = ssum[r] * invT;
    __syncthreads();
    #pragma unroll
    for (int r = 0; r < R_PB; ++r)
        out[(size_t)(r0 + r) * N_NEU + q] = stg[r * N_NEU + q];   // coalesced
    __syncthreads();

    #pragma unroll
    for (int r = 0; r < R_PB; ++r) stg[r * N_NEU + n] = v0v[r];
    __syncthreads();
    #pragma unroll
    for (int r = 0; r < R_PB; ++r)
        out[BN + (size_t)(r0 + r) * N_NEU + q] = stg[r * N_NEU + q];
    __syncthreads();

    #pragma unroll
    for (int r = 0; r < R_PB; ++r) stg[r * N_NEU + n] = c0v[r];
    __syncthreads();
    #pragma unroll
    for (int r = 0; r < R_PB; ++r)
        out[2 * BN + (size_t)(r0 + r) * N_NEU + q] = stg[r * N_NEU + q];
}

// ---------------------------------------------------------------- launch
extern "C" void kernel_launch(void* const* d_in, const int* in_sizes, int n_in,
                              void* d_out, int out_size, void* d_ws, size_t ws_size,
                              hipStream_t stream)
{
    const float* rates = (const float*)d_in[0];
    const float* inW   = (const float*)d_in[1];
    const float* W     = (const float*)d_in[2];
    const float* vin   = (const float*)d_in[3];
    const float* cin   = (const float*)d_in[4];
    const int*   nst   = (const int*)d_in[5];
    uint32_t* ws = (uint32_t*)d_ws;
    float* out = (float*)d_out;
    (void)in_sizes; (void)n_in; (void)out_size; (void)ws_size;

    // zero CNT (harness poisons d_ws to 0xAA before every call)
    hipMemsetAsync((char*)d_ws + WS_CNT, 0, 2048, stream);

    lsm_count<<<128, 256, 0, stream>>>(W, ws);
    lsm_sort<<<1, 512, 0, stream>>>(ws);
    lsm_fill<<<N_NEU, 64, 0, stream>>>(W, ws);
    lsm_main<<<NBLK, 512, 0, stream>>>(rates, inW, vin, cin, nst, ws, out);
}

// Round 16
// 371.544 us; speedup vs baseline: 1.1536x; 1.1536x over previous
//
#include <hip/hip_runtime.h>
#include <stdint.h>

// LiquidStateMachine on MI355X — round 16.
// r15 spilled (VGPR capped at exactly 128 @512thr; cap = 65536/threads).
// r16 = r14 base + register-budgeted depth:
//  (1) THIRD streamed weight buffer: streamed weights now issued 2-3
//      chunks (~350-700cyc) before consume vs r14's 1 chunk (~175cyc) —
//      the one exposed latency left (L2 ~200-400cyc). Gathers stay 2-deep
//      (LDS ~120cyc, covered). +8 regs.
//  (2) ssum packed into 2 byte-counter u32s (counts<=64/byte). -6 regs.
//  (3) r15's coalesced prologue/epilogue LDS staging (outside the loop,
//      register-free; unmeasured in r15 due to the spill).
// Budget ~114 <= 128. Canary: WRITE_SIZE must stay ~12.3MB.
// Keeps: ping-pong spike bufs (1 barrier/step), SIMD balance, resident
// chunk-0..2 weights, full index-stream register preload.
// Weights EXACT fp32 (r2: rounding flips spikes); u8 spike 0/1 exact.
//
// d_ws layout (bytes):
//   0      PERM[512]  sorted-rank -> column
//   2048   RANK[512]  column -> sorted rank
//   4096   CNT[512]   nnz per column          (zeroed via hipMemsetAsync)
//   8192   CNTW[8]    per-group padded trip count (multiple of 8)
//   8256   IBASE[8]   per-group byte base into IDX region
//   8320   WBASE[8]   per-group byte base into WT region
//   16384  IDX        u16 spike-offset (8k):
//                     byte = ib + (j>>3)*1024 + lane*16 + (j&7)*2
//   81920  WT         f32 w: byte = wb + (j>>3)*2048 + lane*32 + (j&7)*4

#define N_NEU 512
#define B_ROWS 2048
#define D_IN 256
#define R_PB 8
#define NBLK (B_ROWS / R_PB)   // 256 blocks x 512 threads = 1 block/CU

#define WS_PERM    0
#define WS_RANK    2048
#define WS_CNT     4096
#define WS_CNTW    8192
#define WS_IBASE   8256
#define WS_WBASE   8320
#define WS_IDX     16384
#define WS_WT      81920

// spike record: 8 bytes (8 rows x u8 0/1) at natural offset 8k
#define SPK_OFF(k)  ((k) << 3)
#define SPK_BUF     4096       // one buffer: 512 neurons x 8 B

// ---------------------------------------------------------------- prep A
__global__ __launch_bounds__(256) void lsm_count(
    const float* __restrict__ W, uint32_t* __restrict__ ws)
{
    int t  = threadIdx.x;
    int k0 = blockIdx.x * 4;
    int c0 = 0, c1 = 0;
    #pragma unroll
    for (int kk = 0; kk < 4; ++kk) {
        const float* row = W + (size_t)(k0 + kk) * N_NEU;
        c0 += (row[t]       != 0.0f) ? 1 : 0;
        c1 += (row[t + 256] != 0.0f) ? 1 : 0;
    }
    if (c0) atomicAdd(&ws[(WS_CNT >> 2) + t],       (uint32_t)c0);
    if (c1) atomicAdd(&ws[(WS_CNT >> 2) + t + 256], (uint32_t)c1);
}

// ---------------------------------------------------------------- prep B
__global__ __launch_bounds__(512) void lsm_sort(uint32_t* __restrict__ ws)
{
    __shared__ int hist[N_NEU + 1];
    __shared__ int csort[N_NEU];
    __shared__ int gcw[8];

    int t = threadIdx.x;
    int creal = (int)ws[(WS_CNT >> 2) + t];
    for (int i = t; i < N_NEU + 1; i += 512) hist[i] = 0;
    __syncthreads();
    atomicAdd(&hist[creal], 1);
    __syncthreads();
    if (t == 0) {
        int acc = 0;
        for (int v = 0; v <= N_NEU; ++v) { int h = hist[v]; hist[v] = acc; acc += h; }
    }
    __syncthreads();
    int rank = atomicAdd(&hist[creal], 1);
    ws[(WS_PERM >> 2) + rank] = (uint32_t)t;
    ws[(WS_RANK >> 2) + t]    = (uint32_t)rank;
    csort[rank] = creal;
    __syncthreads();
    if (t < 8) {
        int cw = csort[t * 64 + 63];         // ascending -> group max is last
        cw = (cw + 7) & ~7;                  // pad to multiple of 8 (one chunk)
        gcw[t] = cw;
        ws[(WS_CNTW >> 2) + t] = (uint32_t)cw;
    }
    __syncthreads();
    if (t == 0) {
        int ai = 0, aw = 0;
        for (int g = 0; g < 8; ++g) {
            ws[(WS_IBASE >> 2) + g] = (uint32_t)ai;
            ws[(WS_WBASE >> 2) + g] = (uint32_t)aw;
            ai += gcw[g] * 64 * 2;           // bytes (u16 per entry)
            aw += gcw[g] * 64 * 4;           // bytes (f32 per entry)
        }
    }
    __syncthreads();
    // pad tail slots of this thread's column (offset 0 -> neuron 0, w=0)
    int wg = rank >> 6, ls = rank & 63;
    int cw = gcw[wg];
    uint32_t ib = ws[(WS_IBASE >> 2) + wg];
    uint32_t wb = ws[(WS_WBASE >> 2) + wg];
    char* base = (char*)ws;
    for (int j = creal; j < cw; ++j) {
        *(unsigned short*)(base + WS_IDX + ib + (j >> 3) * 1024 + ls * 16 + (j & 7) * 2) = 0;
        *(float*)(base + WS_WT + wb + (j >> 3) * 2048 + ls * 32 + (j & 7) * 4) = 0.0f;
    }
}

// ---------------------------------------------------------------- prep C
__global__ __launch_bounds__(64) void lsm_fill(
    const float* __restrict__ W, uint32_t* __restrict__ ws)
{
    int c    = blockIdx.x;
    int lane = threadIdx.x;
    char* base = (char*)ws;
    uint32_t rank = ws[(WS_RANK >> 2) + c];
    int wg = (int)(rank >> 6), ls = (int)(rank & 63);
    uint32_t ib = ws[(WS_IBASE >> 2) + wg];
    uint32_t wb = ws[(WS_WBASE >> 2) + wg];

    __shared__ int ctr;
    if (lane == 0) ctr = 0;
    __syncthreads();

    for (int k = lane; k < N_NEU; k += 64) {
        float wv = W[(size_t)k * N_NEU + c];
        if (wv != 0.0f) {
            int j = atomicAdd(&ctr, 1);      // order within column irrelevant
            *(unsigned short*)(base + WS_IDX + ib + (j >> 3) * 1024 + ls * 16 + (j & 7) * 2)
                = (unsigned short)SPK_OFF(k);
            *(float*)(base + WS_WT + wb + (j >> 3) * 2048 + ls * 32 + (j & 7) * 4) = wv;
        }
    }
}

// -------- spill-proof pipeline macros (all scalars, no arrays/fns) --------
// B = spike-buffer base for this step (smem + (t&1)*SPK_BUF)
#define GATH(P, X, B) \
    P##0 = *(const uint2*)((B) + ((X).x & 0xffffu)); \
    P##1 = *(const uint2*)((B) + ((X).x >> 16));     \
    P##2 = *(const uint2*)((B) + ((X).y & 0xffffu)); \
    P##3 = *(const uint2*)((B) + ((X).y >> 16));     \
    P##4 = *(const uint2*)((B) + ((X).z & 0xffffu)); \
    P##5 = *(const uint2*)((B) + ((X).z >> 16));     \
    P##6 = *(const uint2*)((B) + ((X).w & 0xffffu)); \
    P##7 = *(const uint2*)((B) + ((X).w >> 16));

// one entry: weight W x 8 rows' u8 spikes ((dw>>8j)&0xff -> v_cvt_f32_ubyteN)
#define C1(S, W) \
    rec0 = fmaf((W), (float)((S).x & 0xffu),         rec0); \
    rec1 = fmaf((W), (float)(((S).x >> 8) & 0xffu),  rec1); \
    rec2 = fmaf((W), (float)(((S).x >> 16) & 0xffu), rec2); \
    rec3 = fmaf((W), (float)((S).x >> 24),           rec3); \
    rec4 = fmaf((W), (float)((S).y & 0xffu),         rec4); \
    rec5 = fmaf((W), (float)(((S).y >> 8) & 0xffu),  rec5); \
    rec6 = fmaf((W), (float)(((S).y >> 16) & 0xffu), rec6); \
    rec7 = fmaf((W), (float)((S).y >> 24),           rec7);

#define CONS(P, WA, WB) \
    C1(P##0, (WA).x) C1(P##1, (WA).y) C1(P##2, (WA).z) C1(P##3, (WA).w) \
    C1(P##4, (WB).x) C1(P##5, (WB).y) C1(P##6, (WB).z) C1(P##7, (WB).w)

#define LDW(WA, WB, K) \
    WA = ((const float4*)(wp0 + (K) * 2048))[0]; \
    WB = ((const float4*)(wp0 + (K) * 2048))[1];

// ---------------------------------------------------------------- main
// LDS map:
//   [0,4096)       spk buffer 0 (u8 x 8 rows per neuron, 8B records @ 8k)
//   [4096,8192)    spk buffer 1 (ping-pong)
//   [8192,24576)   stg: 16KB scratch — state staging / rates rl / out staging
__global__ __launch_bounds__(512, 1)
void lsm_main(
    const float* __restrict__ rates, const float* __restrict__ inW,
    const float* __restrict__ vin,   const float* __restrict__ cin,
    const int* __restrict__ nsteps_p,
    const uint32_t* __restrict__ ws, float* __restrict__ out)
{
    __shared__ __align__(16) unsigned char smem[2 * SPK_BUF + 16384];
    float* stg = (float*)(smem + 2 * SPK_BUF);
    float* rl  = stg;

    int q    = threadIdx.x;
    int blk  = blockIdx.x;
    int r0   = blk * R_PB;
    int w    = q >> 6;
    int lane = q & 63;
    // SIMD balance: waves {s, s+4} share SIMD s; give them groups {s, 7-s}
    int wg   = (w < 4) ? w : (11 - w);
    int n    = (int)ws[(WS_PERM >> 2) + wg * 64 + lane];
    int cw   = (int)ws[(WS_CNTW >> 2) + wg];     // wave-uniform
    int nit  = cw >> 3;                          // 8-entry chunks (<=12)
    const char* ip0 = (const char*)ws + WS_IDX + ws[(WS_IBASE >> 2) + wg]
                    + lane * 16;
    const char* wp0 = (const char*)ws + WS_WT  + ws[(WS_WBASE >> 2) + wg]
                    + lane * 32;
    int spk_n = SPK_OFF(n);                      // this column's record

    // ---- coalesced state staging: cin then vin through LDS ----
    float c0v[R_PB], v0v[R_PB];
    #pragma unroll
    for (int r = 0; r < R_PB; ++r)
        stg[r * N_NEU + q] = cin[(size_t)(r0 + r) * N_NEU + q];   // coalesced
    __syncthreads();
    #pragma unroll
    for (int r = 0; r < R_PB; ++r) c0v[r] = stg[r * N_NEU + n];
    __syncthreads();
    #pragma unroll
    for (int r = 0; r < R_PB; ++r)
        stg[r * N_NEU + q] = vin[(size_t)(r0 + r) * N_NEU + q];   // coalesced
    __syncthreads();
    #pragma unroll
    for (int r = 0; r < R_PB; ++r) v0v[r] = stg[r * N_NEU + n];
    __syncthreads();

    // ---- rates -> rl (coalesced), then I-dot ----
    ((float4*)rl)[q] = ((const float4*)(rates + (size_t)r0 * D_IN))[q];
    __syncthreads();

    float I[R_PB] = {0.f, 0.f, 0.f, 0.f, 0.f, 0.f, 0.f, 0.f};
    {
        const float4* wrow = (const float4*)(inW + (size_t)n * D_IN);
        for (int d4 = 0; d4 < D_IN / 4; ++d4) {
            float4 wv = wrow[d4];
            #pragma unroll
            for (int r = 0; r < R_PB; ++r) {
                const float* rr = rl + r * D_IN + d4 * 4;   // LDS broadcast
                I[r] += wv.x * rr[0] + wv.y * rr[1] + wv.z * rr[2] + wv.w * rr[3];
            }
        }
    }

    // initial u8 spikes -> buffer 0
    uint2 sini = make_uint2(0u, 0u);
    #pragma unroll
    for (int r = 0; r < R_PB; ++r) {
        unsigned bit = (c0v[r] > 0.f) ? 1u : 0u;
        if (r < 4) sini.x |= bit << (r * 8);
        else       sini.y |= bit << ((r - 4) * 8);
    }
    *(uint2*)(smem + spk_n) = sini;

    // packed spike counters: byte r = count of (v>0) for row r (<=64, fits)
    unsigned ssx = 0u, ssy = 0u;

    // preload ENTIRE index stream into registers (constant across steps)
    uint4 xr0, xr1, xr2, xr3, xr4, xr5, xr6, xr7, xr8, xr9, xr10, xr11;
    const uint4 xz = make_uint4(0u, 0u, 0u, 0u);
    xr0  =              *(const uint4*)(ip0);
    xr1  = (1  < nit) ? *(const uint4*)(ip0 + 1024)  : xz;
    xr2  = (2  < nit) ? *(const uint4*)(ip0 + 2048)  : xz;
    xr3  = (3  < nit) ? *(const uint4*)(ip0 + 3072)  : xz;
    xr4  = (4  < nit) ? *(const uint4*)(ip0 + 4096)  : xz;
    xr5  = (5  < nit) ? *(const uint4*)(ip0 + 5120)  : xz;
    xr6  = (6  < nit) ? *(const uint4*)(ip0 + 6144)  : xz;
    xr7  = (7  < nit) ? *(const uint4*)(ip0 + 7168)  : xz;
    xr8  = (8  < nit) ? *(const uint4*)(ip0 + 8192)  : xz;
    xr9  = (9  < nit) ? *(const uint4*)(ip0 + 9216)  : xz;
    xr10 = (10 < nit) ? *(const uint4*)(ip0 + 10240) : xz;
    xr11 = (11 < nit) ? *(const uint4*)(ip0 + 11264) : xz;

    // resident weights for chunks 0-2 (loop-invariant)
    float4 rw0a, rw0b, rw1a, rw1b, rw2a, rw2b;
    const float4 fz = make_float4(0.f, 0.f, 0.f, 0.f);
    rw0a = ((const float4*)wp0)[0];
    rw0b = ((const float4*)wp0)[1];
    rw1a = (1 < nit) ? ((const float4*)(wp0 + 2048))[0] : fz;
    rw1b = (1 < nit) ? ((const float4*)(wp0 + 2048))[1] : fz;
    rw2a = (2 < nit) ? ((const float4*)(wp0 + 4096))[0] : fz;
    rw2b = (2 < nit) ? ((const float4*)(wp0 + 4096))[1] : fz;

    const float AS   = (float)0.8187307530779818;   // exp(-1/5)
    const float OMAS = (float)(1.0 - 0.8187307530779818);
    const float AM   = (float)0.9512294245007140;   // exp(-1/20)
    const float OMAM = (float)(1.0 - 0.9512294245007140);

    int T = nsteps_p[0];
    __syncthreads();   // initial spikes visible

    #pragma unroll 1
    for (int t = 0; t < T; ++t) {
        const unsigned char* sb = smem + ((t & 1) ? SPK_BUF : 0);   // read buf
        unsigned char*       db = smem + ((t & 1) ? 0 : SPK_BUF);   // write buf

        float rec0 = 0.f, rec1 = 0.f, rec2 = 0.f, rec3 = 0.f;
        float rec4 = 0.f, rec5 = 0.f, rec6 = 0.f, rec7 = 0.f;
        uint2 a0, a1, a2, a3, a4, a5, a6, a7;
        uint2 b0, b1, b2, b3, b4, b5, b6, b7;
        float4 waA, wbA, waB, wbB, waC, wbC;

        // streamed weights 2-3 chunks ahead (3 buffers); gathers 2-deep.
        GATH(a, xr0, sb)
        if (3 < nit) { LDW(waA, wbA, 3) }
        if (4 < nit) { LDW(waB, wbB, 4) }
        if (1 < nit) { GATH(b, xr1, sb) }
        CONS(a, rw0a, rw0b)
        if (1 < nit) {
            if (2 < nit) { GATH(a, xr2, sb) }
            CONS(b, rw1a, rw1b)
        }
        if (2 < nit) {
            if (5 < nit) { LDW(waC, wbC, 5) }
            if (3 < nit) { GATH(b, xr3, sb) }
            CONS(a, rw2a, rw2b)
        }
        if (3 < nit) {
            if (4 < nit) { GATH(a, xr4, sb) }
            CONS(b, waA, wbA)
            if (6 < nit) { LDW(waA, wbA, 6) }
        }
        if (4 < nit) {
            if (5 < nit) { GATH(b, xr5, sb) }
            CONS(a, waB, wbB)
            if (7 < nit) { LDW(waB, wbB, 7) }
        }
        if (5 < nit) {
            if (6 < nit) { GATH(a, xr6, sb) }
            CONS(b, waC, wbC)
            if (8 < nit) { LDW(waC, wbC, 8) }
        }
        if (6 < nit) {
            if (7 < nit) { GATH(b, xr7, sb) }
            CONS(a, waA, wbA)
            if (9 < nit) { LDW(waA, wbA, 9) }
        }
        if (7 < nit) {
            if (8 < nit) { GATH(a, xr8, sb) }
            CONS(b, waB, wbB)
            if (10 < nit) { LDW(waB, wbB, 10) }
        }
        if (8 < nit) {
            if (9 < nit) { GATH(b, xr9, sb) }
            CONS(a, waC, wbC)
            if (11 < nit) { LDW(waC, wbC, 11) }
        }
        if (9 < nit) {
            if (10 < nit) { GATH(a, xr10, sb) }
            CONS(b, waA, wbA)
        }
        if (10 < nit) {
            if (11 < nit) { GATH(b, xr11, sb) }
            CONS(a, waB, wbB)
        }
        if (11 < nit) {
            CONS(b, waC, wbC)
        }

        // update; write new spikes to the other buffer (no WAR hazard)
        uint2 ns = make_uint2(0u, 0u);
        unsigned vbx = 0u, vby = 0u;
        {
            float rca[R_PB] = {rec0, rec1, rec2, rec3, rec4, rec5, rec6, rec7};
            #pragma unroll
            for (int r = 0; r < R_PB; ++r) {
                c0v[r] = AS * c0v[r] + OMAS * (I[r] + rca[r]);
                v0v[r] = AM * v0v[r] + OMAM * c0v[r];
                unsigned cb = (c0v[r] > 0.f) ? 1u : 0u;
                unsigned vb = (v0v[r] > 0.f) ? 1u : 0u;
                if (r < 4) { ns.x |= cb << (r * 8);       vbx |= vb << (r * 8); }
                else       { ns.y |= cb << ((r - 4) * 8); vby |= vb << ((r - 4) * 8); }
            }
        }
        ssx += vbx;   // bytewise counters, max 64 < 256: no carry between bytes
        ssy += vby;
        *(uint2*)(db + spk_n) = ns;
        __syncthreads();   // new spikes visible; old buffer free for reuse
    }

    // ---- coalesced epilogue: stage each quantity through LDS ----
    float invT = 1.0f / (float)T;
    size_t BN = (size_t)B_ROWS * N_NEU;

    #pragma unroll
    for (int r = 0; r < R_PB; ++r) {
        unsigned cnt = (r < 4) ? ((ssx >> (r * 8)) & 0xffu)
                               : ((ssy >> ((r - 4) * 8)) & 0xffu);
        stg[r * N_NEU + n] = (float)cnt * invT;
    }
    __syncthreads();
    #pragma unroll
    for (int r = 0; r < R_PB; ++r)
        out[(size_t)(r0 + r) * N_NEU + q] = stg[r * N_NEU + q];   // coalesced
    __syncthreads();

    #pragma unroll
    for (int r = 0; r < R_PB; ++r) stg[r * N_NEU + n] = v0v[r];
    __syncthreads();
    #pragma unroll
    for (int r = 0; r < R_PB; ++r)
        out[BN + (size_t)(r0 + r) * N_NEU + q] = stg[r * N_NEU + q];
    __syncthreads();

    #pragma unroll
    for (int r = 0; r < R_PB; ++r) stg[r * N_NEU + n] = c0v[r];
    __syncthreads();
    #pragma unroll
    for (int r = 0; r < R_PB; ++r)
        out[2 * BN + (size_t)(r0 + r) * N_NEU + q] = stg[r * N_NEU + q];
}

// ---------------------------------------------------------------- launch
extern "C" void kernel_launch(void* const* d_in, const int* in_sizes, int n_in,
                              void* d_out, int out_size, void* d_ws, size_t ws_size,
                              hipStream_t stream)
{
    const float* rates = (const float*)d_in[0];
    const float* inW   = (const float*)d_in[1];
    const float* W     = (const float*)d_in[2];
    const float* vin   = (const float*)d_in[3];
    const float* cin   = (const float*)d_in[4];
    const int*   nst   = (const int*)d_in[5];
    uint32_t* ws = (uint32_t*)d_ws;
    float* out = (float*)d_out;
    (void)in_sizes; (void)n_in; (void)out_size; (void)ws_size;

    // zero CNT (harness poisons d_ws to 0xAA before every call)
    hipMemsetAsync((char*)d_ws + WS_CNT, 0, 2048, stream);

    lsm_count<<<128, 256, 0, stream>>>(W, ws);
    lsm_sort<<<1, 512, 0, stream>>>(ws);
    lsm_fill<<<N_NEU, 64, 0, stream>>>(W, ws);
    lsm_main<<<NBLK, 512, 0, stream>>>(rates, inW, vin, cin, nst, ws, out);
}

// Round 17
// 328.681 us; speedup vs baseline: 1.3040x; 1.1304x over previous
//
#include <hip/hip_runtime.h>
#include <stdint.h>

// LiquidStateMachine on MI355X — round 17.
// r12/r14/r16 all ~307-316us: four orthogonal latency attacks neutral.
// Pipe re-read: VALU is the busiest pipe (65% busy = ~7.7K of 11.8K
// cyc/step; LDS only 42%). Half the inner-loop VALU is v_cvt_f32_ubyte.
// r17: spikes stored as f16 0/1 pairs (16B records @16k, r5's layout),
// consumed with v_fma_mix_f32 (f32 acc += f32 w * f16 spike, ONE instr,
// op_sel picks the half) -> 72 VALU/chunk vs 136. Register compensation:
// drop resident rw weights (r14: neutral) and 3rd weight buffer; f16
// gather sets are +32 regs -> est ~120 <= 128 cap.
// Weights EXACT fp32 (r2: rounding flips spikes); f16 spike 0/1 exact,
// w*1.0f16 exact in fp32 -> only summation order differs from reference.
//
// d_ws layout (bytes):
//   0      PERM[512]  sorted-rank -> column
//   2048   RANK[512]  column -> sorted rank
//   4096   CNT[512]   nnz per column          (zeroed via hipMemsetAsync)
//   8192   CNTW[8]    per-group padded trip count (multiple of 8)
//   8256   IBASE[8]   per-group byte base into IDX region
//   8320   WBASE[8]   per-group byte base into WT region
//   16384  IDX        u16 spike-offset (16k):
//                     byte = ib + (j>>3)*1024 + lane*16 + (j&7)*2
//   81920  WT         f32 w: byte = wb + (j>>3)*2048 + lane*32 + (j&7)*4

#define N_NEU 512
#define B_ROWS 2048
#define D_IN 256
#define R_PB 8
#define NBLK (B_ROWS / R_PB)   // 256 blocks x 512 threads = 1 block/CU

#define WS_PERM    0
#define WS_RANK    2048
#define WS_CNT     4096
#define WS_CNTW    8192
#define WS_IBASE   8256
#define WS_WBASE   8320
#define WS_IDX     16384
#define WS_WT      81920

// spike record: 16 bytes (8 rows x f16 0/1) at natural offset 16k
#define SPK_OFF(k)  ((k) << 4)
#define SPK_BUF     8192       // one buffer: 512 neurons x 16 B

#define H16_ONE 0x3C00u        // f16 1.0

// ---------------------------------------------------------------- prep A
__global__ __launch_bounds__(256) void lsm_count(
    const float* __restrict__ W, uint32_t* __restrict__ ws)
{
    int t  = threadIdx.x;
    int k0 = blockIdx.x * 4;
    int c0 = 0, c1 = 0;
    #pragma unroll
    for (int kk = 0; kk < 4; ++kk) {
        const float* row = W + (size_t)(k0 + kk) * N_NEU;
        c0 += (row[t]       != 0.0f) ? 1 : 0;
        c1 += (row[t + 256] != 0.0f) ? 1 : 0;
    }
    if (c0) atomicAdd(&ws[(WS_CNT >> 2) + t],       (uint32_t)c0);
    if (c1) atomicAdd(&ws[(WS_CNT >> 2) + t + 256], (uint32_t)c1);
}

// ---------------------------------------------------------------- prep B
__global__ __launch_bounds__(512) void lsm_sort(uint32_t* __restrict__ ws)
{
    __shared__ int hist[N_NEU + 1];
    __shared__ int csort[N_NEU];
    __shared__ int gcw[8];

    int t = threadIdx.x;
    int creal = (int)ws[(WS_CNT >> 2) + t];
    for (int i = t; i < N_NEU + 1; i += 512) hist[i] = 0;
    __syncthreads();
    atomicAdd(&hist[creal], 1);
    __syncthreads();
    if (t == 0) {
        int acc = 0;
        for (int v = 0; v <= N_NEU; ++v) { int h = hist[v]; hist[v] = acc; acc += h; }
    }
    __syncthreads();
    int rank = atomicAdd(&hist[creal], 1);
    ws[(WS_PERM >> 2) + rank] = (uint32_t)t;
    ws[(WS_RANK >> 2) + t]    = (uint32_t)rank;
    csort[rank] = creal;
    __syncthreads();
    if (t < 8) {
        int cw = csort[t * 64 + 63];         // ascending -> group max is last
        cw = (cw + 7) & ~7;                  // pad to multiple of 8 (one chunk)
        gcw[t] = cw;
        ws[(WS_CNTW >> 2) + t] = (uint32_t)cw;
    }
    __syncthreads();
    if (t == 0) {
        int ai = 0, aw = 0;
        for (int g = 0; g < 8; ++g) {
            ws[(WS_IBASE >> 2) + g] = (uint32_t)ai;
            ws[(WS_WBASE >> 2) + g] = (uint32_t)aw;
            ai += gcw[g] * 64 * 2;           // bytes (u16 per entry)
            aw += gcw[g] * 64 * 4;           // bytes (f32 per entry)
        }
    }
    __syncthreads();
    // pad tail slots of this thread's column (offset 0 -> neuron 0, w=0)
    int wg = rank >> 6, ls = rank & 63;
    int cw = gcw[wg];
    uint32_t ib = ws[(WS_IBASE >> 2) + wg];
    uint32_t wb = ws[(WS_WBASE >> 2) + wg];
    char* base = (char*)ws;
    for (int j = creal; j < cw; ++j) {
        *(unsigned short*)(base + WS_IDX + ib + (j >> 3) * 1024 + ls * 16 + (j & 7) * 2) = 0;
        *(float*)(base + WS_WT + wb + (j >> 3) * 2048 + ls * 32 + (j & 7) * 4) = 0.0f;
    }
}

// ---------------------------------------------------------------- prep C
__global__ __launch_bounds__(64) void lsm_fill(
    const float* __restrict__ W, uint32_t* __restrict__ ws)
{
    int c    = blockIdx.x;
    int lane = threadIdx.x;
    char* base = (char*)ws;
    uint32_t rank = ws[(WS_RANK >> 2) + c];
    int wg = (int)(rank >> 6), ls = (int)(rank & 63);
    uint32_t ib = ws[(WS_IBASE >> 2) + wg];
    uint32_t wb = ws[(WS_WBASE >> 2) + wg];

    __shared__ int ctr;
    if (lane == 0) ctr = 0;
    __syncthreads();

    for (int k = lane; k < N_NEU; k += 64) {
        float wv = W[(size_t)k * N_NEU + c];
        if (wv != 0.0f) {
            int j = atomicAdd(&ctr, 1);      // order within column irrelevant
            *(unsigned short*)(base + WS_IDX + ib + (j >> 3) * 1024 + ls * 16 + (j & 7) * 2)
                = (unsigned short)SPK_OFF(k);
            *(float*)(base + WS_WT + wb + (j >> 3) * 2048 + ls * 32 + (j & 7) * 4) = wv;
        }
    }
}

// -------- spill-proof pipeline macros (all scalars, no arrays/fns) --------
// B = spike-buffer base for this step; offsets pre-scaled to 16k.
#define GATH(P, X, B) \
    P##0 = *(const uint4*)((B) + ((X).x & 0xffffu)); \
    P##1 = *(const uint4*)((B) + ((X).x >> 16));     \
    P##2 = *(const uint4*)((B) + ((X).y & 0xffffu)); \
    P##3 = *(const uint4*)((B) + ((X).y >> 16));     \
    P##4 = *(const uint4*)((B) + ((X).z & 0xffffu)); \
    P##5 = *(const uint4*)((B) + ((X).z >> 16));     \
    P##6 = *(const uint4*)((B) + ((X).w & 0xffffu)); \
    P##7 = *(const uint4*)((B) + ((X).w >> 16));

// mixed-precision FMA: acc(f32) += w(f32) * f16 half of S (lo/hi)
#define FMIX_LO(ACC, WV, S) \
    asm("v_fma_mix_f32 %0, %1, %2, %0 op_sel:[0,0,0] op_sel_hi:[0,1,0]" \
        : "+v"(ACC) : "v"(WV), "v"(S));
#define FMIX_HI(ACC, WV, S) \
    asm("v_fma_mix_f32 %0, %1, %2, %0 op_sel:[0,1,0] op_sel_hi:[0,1,0]" \
        : "+v"(ACC) : "v"(WV), "v"(S));

// one entry: weight WV x 8 rows' f16 spikes (uint4 S = 4 f16-pairs)
#define C1(S, WV) \
    FMIX_LO(rec0, WV, (S).x) FMIX_HI(rec1, WV, (S).x) \
    FMIX_LO(rec2, WV, (S).y) FMIX_HI(rec3, WV, (S).y) \
    FMIX_LO(rec4, WV, (S).z) FMIX_HI(rec5, WV, (S).z) \
    FMIX_LO(rec6, WV, (S).w) FMIX_HI(rec7, WV, (S).w)

#define CONS(P, WA, WB) \
    C1(P##0, (WA).x) C1(P##1, (WA).y) C1(P##2, (WA).z) C1(P##3, (WA).w) \
    C1(P##4, (WB).x) C1(P##5, (WB).y) C1(P##6, (WB).z) C1(P##7, (WB).w)

#define LDW(WA, WB, K) \
    WA = ((const float4*)(wp0 + (K) * 2048))[0]; \
    WB = ((const float4*)(wp0 + (K) * 2048))[1];

// ---------------------------------------------------------------- main
// LDS map:
//   [0,8192)       spk buffer 0 (f16 x 8 rows per neuron, 16B @ 16k)
//   [8192,16384)   spk buffer 1 (ping-pong)
//   [16384,32768)  stg: 16KB scratch — state staging / rates rl / out staging
__global__ __launch_bounds__(512, 1)
void lsm_main(
    const float* __restrict__ rates, const float* __restrict__ inW,
    const float* __restrict__ vin,   const float* __restrict__ cin,
    const int* __restrict__ nsteps_p,
    const uint32_t* __restrict__ ws, float* __restrict__ out)
{
    __shared__ __align__(16) unsigned char smem[2 * SPK_BUF + 16384];
    float* stg = (float*)(smem + 2 * SPK_BUF);
    float* rl  = stg;

    int q    = threadIdx.x;
    int blk  = blockIdx.x;
    int r0   = blk * R_PB;
    int w    = q >> 6;
    int lane = q & 63;
    // SIMD balance: waves {s, s+4} share SIMD s; give them groups {s, 7-s}
    int wg   = (w < 4) ? w : (11 - w);
    int n    = (int)ws[(WS_PERM >> 2) + wg * 64 + lane];
    int cw   = (int)ws[(WS_CNTW >> 2) + wg];     // wave-uniform
    int nit  = cw >> 3;                          // 8-entry chunks (<=12)
    const char* ip0 = (const char*)ws + WS_IDX + ws[(WS_IBASE >> 2) + wg]
                    + lane * 16;
    const char* wp0 = (const char*)ws + WS_WT  + ws[(WS_WBASE >> 2) + wg]
                    + lane * 32;
    int spk_n = SPK_OFF(n);                      // this column's record

    // ---- coalesced state staging: cin then vin through LDS ----
    float c0v[R_PB], v0v[R_PB];
    #pragma unroll
    for (int r = 0; r < R_PB; ++r)
        stg[r * N_NEU + q] = cin[(size_t)(r0 + r) * N_NEU + q];   // coalesced
    __syncthreads();
    #pragma unroll
    for (int r = 0; r < R_PB; ++r) c0v[r] = stg[r * N_NEU + n];
    __syncthreads();
    #pragma unroll
    for (int r = 0; r < R_PB; ++r)
        stg[r * N_NEU + q] = vin[(size_t)(r0 + r) * N_NEU + q];   // coalesced
    __syncthreads();
    #pragma unroll
    for (int r = 0; r < R_PB; ++r) v0v[r] = stg[r * N_NEU + n];
    __syncthreads();

    // ---- rates -> rl (coalesced), then I-dot ----
    ((float4*)rl)[q] = ((const float4*)(rates + (size_t)r0 * D_IN))[q];
    __syncthreads();

    float I[R_PB] = {0.f, 0.f, 0.f, 0.f, 0.f, 0.f, 0.f, 0.f};
    {
        const float4* wrow = (const float4*)(inW + (size_t)n * D_IN);
        for (int d4 = 0; d4 < D_IN / 4; ++d4) {
            float4 wv = wrow[d4];
            #pragma unroll
            for (int r = 0; r < R_PB; ++r) {
                const float* rr = rl + r * D_IN + d4 * 4;   // LDS broadcast
                I[r] += wv.x * rr[0] + wv.y * rr[1] + wv.z * rr[2] + wv.w * rr[3];
            }
        }
    }

    // initial f16 spikes -> buffer 0
    uint4 sini = make_uint4(0u, 0u, 0u, 0u);
    #pragma unroll
    for (int r = 0; r < R_PB; ++r) {
        unsigned hb = (c0v[r] > 0.f) ? H16_ONE : 0u;
        unsigned sh = (r & 1) ? 16 : 0;
        if (r < 2)      sini.x |= hb << sh;
        else if (r < 4) sini.y |= hb << sh;
        else if (r < 6) sini.z |= hb << sh;
        else            sini.w |= hb << sh;
    }
    *(uint4*)(smem + spk_n) = sini;

    // packed spike counters: byte r = count of (v>0) for row r (<=64, fits)
    unsigned ssx = 0u, ssy = 0u;

    // preload ENTIRE index stream into registers (constant across steps)
    uint4 xr0, xr1, xr2, xr3, xr4, xr5, xr6, xr7, xr8, xr9, xr10, xr11;
    const uint4 xz = make_uint4(0u, 0u, 0u, 0u);
    xr0  =              *(const uint4*)(ip0);
    xr1  = (1  < nit) ? *(const uint4*)(ip0 + 1024)  : xz;
    xr2  = (2  < nit) ? *(const uint4*)(ip0 + 2048)  : xz;
    xr3  = (3  < nit) ? *(const uint4*)(ip0 + 3072)  : xz;
    xr4  = (4  < nit) ? *(const uint4*)(ip0 + 4096)  : xz;
    xr5  = (5  < nit) ? *(const uint4*)(ip0 + 5120)  : xz;
    xr6  = (6  < nit) ? *(const uint4*)(ip0 + 6144)  : xz;
    xr7  = (7  < nit) ? *(const uint4*)(ip0 + 7168)  : xz;
    xr8  = (8  < nit) ? *(const uint4*)(ip0 + 8192)  : xz;
    xr9  = (9  < nit) ? *(const uint4*)(ip0 + 9216)  : xz;
    xr10 = (10 < nit) ? *(const uint4*)(ip0 + 10240) : xz;
    xr11 = (11 < nit) ? *(const uint4*)(ip0 + 11264) : xz;

    const float AS   = (float)0.8187307530779818;   // exp(-1/5)
    const float OMAS = (float)(1.0 - 0.8187307530779818);
    const float AM   = (float)0.9512294245007140;   // exp(-1/20)
    const float OMAM = (float)(1.0 - 0.9512294245007140);

    int T = nsteps_p[0];
    __syncthreads();   // initial spikes visible

    #pragma unroll 1
    for (int t = 0; t < T; ++t) {
        const unsigned char* sb = smem + ((t & 1) ? SPK_BUF : 0);   // read buf
        unsigned char*       db = smem + ((t & 1) ? 0 : SPK_BUF);   // write buf

        float rec0 = 0.f, rec1 = 0.f, rec2 = 0.f, rec3 = 0.f;
        float rec4 = 0.f, rec5 = 0.f, rec6 = 0.f, rec7 = 0.f;
        uint4 a0, a1, a2, a3, a4, a5, a6, a7;
        uint4 b0, b1, b2, b3, b4, b5, b6, b7;
        float4 waA, wbA, waB, wbB;

        // 2-deep pipeline: gather addrs from registers, weights 2-deep.
        LDW(waA, wbA, 0)
        GATH(a, xr0, sb)
        if (1 < nit)  { LDW(waB, wbB, 1)  GATH(b, xr1, sb)  }
        CONS(a, waA, wbA)
        if (1 < nit)  {
            if (2 < nit)  { LDW(waA, wbA, 2)  GATH(a, xr2, sb)  }
            CONS(b, waB, wbB)
        }
        if (2 < nit)  {
            if (3 < nit)  { LDW(waB, wbB, 3)  GATH(b, xr3, sb)  }
            CONS(a, waA, wbA)
        }
        if (3 < nit)  {
            if (4 < nit)  { LDW(waA, wbA, 4)  GATH(a, xr4, sb)  }
            CONS(b, waB, wbB)
        }
        if (4 < nit)  {
            if (5 < nit)  { LDW(waB, wbB, 5)  GATH(b, xr5, sb)  }
            CONS(a, waA, wbA)
        }
        if (5 < nit)  {
            if (6 < nit)  { LDW(waA, wbA, 6)  GATH(a, xr6, sb)  }
            CONS(b, waB, wbB)
        }
        if (6 < nit)  {
            if (7 < nit)  { LDW(waB, wbB, 7)  GATH(b, xr7, sb)  }
            CONS(a, waA, wbA)
        }
        if (7 < nit)  {
            if (8 < nit)  { LDW(waA, wbA, 8)  GATH(a, xr8, sb)  }
            CONS(b, waB, wbB)
        }
        if (8 < nit)  {
            if (9 < nit)  { LDW(waB, wbB, 9)  GATH(b, xr9, sb)  }
            CONS(a, waA, wbA)
        }
        if (9 < nit)  {
            if (10 < nit) { LDW(waA, wbA, 10) GATH(a, xr10, sb) }
            CONS(b, waB, wbB)
        }
        if (10 < nit) {
            if (11 < nit) { LDW(waB, wbB, 11) GATH(b, xr11, sb) }
            CONS(a, waA, wbA)
        }
        if (11 < nit) {
            CONS(b, waB, wbB)
        }

        // update; write new f16 spikes to the other buffer (no WAR hazard)
        uint4 ns = make_uint4(0u, 0u, 0u, 0u);
        unsigned vbx = 0u, vby = 0u;
        {
            float rca[R_PB] = {rec0, rec1, rec2, rec3, rec4, rec5, rec6, rec7};
            #pragma unroll
            for (int r = 0; r < R_PB; ++r) {
                c0v[r] = AS * c0v[r] + OMAS * (I[r] + rca[r]);
                v0v[r] = AM * v0v[r] + OMAM * c0v[r];
                unsigned hb = (c0v[r] > 0.f) ? H16_ONE : 0u;
                unsigned vb = (v0v[r] > 0.f) ? 1u : 0u;
                unsigned sh = (r & 1) ? 16 : 0;
                if (r < 2)      ns.x |= hb << sh;
                else if (r < 4) ns.y |= hb << sh;
                else if (r < 6) ns.z |= hb << sh;
                else            ns.w |= hb << sh;
                if (r < 4) vbx |= vb << (r * 8);
                else       vby |= vb << ((r - 4) * 8);
            }
        }
        ssx += vbx;   // bytewise counters, max 64 < 256: no inter-byte carry
        ssy += vby;
        *(uint4*)(db + spk_n) = ns;
        __syncthreads();   // new spikes visible; old buffer free for reuse
    }

    // ---- coalesced epilogue: stage each quantity through LDS ----
    float invT = 1.0f / (float)T;
    size_t BN = (size_t)B_ROWS * N_NEU;

    #pragma unroll
    for (int r = 0; r < R_PB; ++r) {
        unsigned cnt = (r < 4) ? ((ssx >> (r * 8)) & 0xffu)
                               : ((ssy >> ((r - 4) * 8)) & 0xffu);
        stg[r * N_NEU + n] = (float)cnt * invT;
    }
    __syncthreads();
    #pragma unroll
    for (int r = 0; r < R_PB; ++r)
        out[(size_t)(r0 + r) * N_NEU + q] = stg[r * N_NEU + q];   // coalesced
    __syncthreads();

    #pragma unroll
    for (int r = 0; r < R_PB; ++r) stg[r * N_NEU + n] = v0v[r];
    __syncthreads();
    #pragma unroll
    for (int r = 0; r < R_PB; ++r)
        out[BN + (size_t)(r0 + r) * N_NEU + q] = stg[r * N_NEU + q];
    __syncthreads();

    #pragma unroll
    for (int r = 0; r < R_PB; ++r) stg[r * N_NEU + n] = c0v[r];
    __syncthreads();
    #pragma unroll
    for (int r = 0; r < R_PB; ++r)
        out[2 * BN + (size_t)(r0 + r) * N_NEU + q] = stg[r * N_NEU + q];
}

// ---------------------------------------------------------------- launch
extern "C" void kernel_launch(void* const* d_in, const int* in_sizes, int n_in,
                              void* d_out, int out_size, void* d_ws, size_t ws_size,
                              hipStream_t stream)
{
    const float* rates = (const float*)d_in[0];
    const float* inW   = (const float*)d_in[1];
    const float* W     = (const float*)d_in[2];
    const float* vin   = (const float*)d_in[3];
    const float* cin   = (const float*)d_in[4];
    const int*   nst   = (const int*)d_in[5];
    uint32_t* ws = (uint32_t*)d_ws;
    float* out = (float*)d_out;
    (void)in_sizes; (void)n_in; (void)out_size; (void)ws_size;

    // zero CNT (harness poisons d_ws to 0xAA before every call)
    hipMemsetAsync((char*)d_ws + WS_CNT, 0, 2048, stream);

    lsm_count<<<128, 256, 0, stream>>>(W, ws);
    lsm_sort<<<1, 512, 0, stream>>>(ws);
    lsm_fill<<<N_NEU, 64, 0, stream>>>(W, ws);
    lsm_main<<<NBLK, 512, 0, stream>>>(rates, inW, vin, cin, nst, ws, out);
}

// Round 18
// 326.128 us; speedup vs baseline: 1.3142x; 1.0078x over previous
//
#include <hip/hip_runtime.h>
#include <stdint.h>

// LiquidStateMachine on MI355X — round 18.
// r17 (265us steady): fma_mix killed the cvt VALU -> LDS pipe now ~85% of
// the wall (464 b128 gathers x 12cyc + 2.8K cyc/step conflicts). A b128's
// floor is 8 accesses/bank; the extra ~6 cyc/instr is per-bank load
// imbalance (random k -> multinomial max ~14 vs mean 8). Record bank-group
// = k mod 8; entry ORDER within each lane's stream is free (summation
// order arbitrary). r18: lsm_fill writes entries sorted by rotated bucket
// r = ((k&7) - (ls&7)) & 7 -> at any slot j the wave's 64 lanes spread
// ~uniformly over the 8 bank-groups = the 8/bank floor. Zero runtime cost.
// Everything else identical to r17 (f16 spike records @16k, v_fma_mix
// consume, 2-deep pipeline, ping-pong bufs, coalesced pro/epilogue).
// Weights EXACT fp32 (r2: rounding flips spikes); f16 spike 0/1 exact.
//
// d_ws layout (bytes):
//   0      PERM[512]  sorted-rank -> column
//   2048   RANK[512]  column -> sorted rank
//   4096   CNT[512]   nnz per column          (zeroed via hipMemsetAsync)
//   8192   CNTW[8]    per-group padded trip count (multiple of 8)
//   8256   IBASE[8]   per-group byte base into IDX region
//   8320   WBASE[8]   per-group byte base into WT region
//   16384  IDX        u16 spike-offset (16k):
//                     byte = ib + (j>>3)*1024 + lane*16 + (j&7)*2
//   81920  WT         f32 w: byte = wb + (j>>3)*2048 + lane*32 + (j&7)*4

#define N_NEU 512
#define B_ROWS 2048
#define D_IN 256
#define R_PB 8
#define NBLK (B_ROWS / R_PB)   // 256 blocks x 512 threads = 1 block/CU

#define WS_PERM    0
#define WS_RANK    2048
#define WS_CNT     4096
#define WS_CNTW    8192
#define WS_IBASE   8256
#define WS_WBASE   8320
#define WS_IDX     16384
#define WS_WT      81920

// spike record: 16 bytes (8 rows x f16 0/1) at natural offset 16k
#define SPK_OFF(k)  ((k) << 4)
#define SPK_BUF     8192       // one buffer: 512 neurons x 16 B

#define H16_ONE 0x3C00u        // f16 1.0

// ---------------------------------------------------------------- prep A
__global__ __launch_bounds__(256) void lsm_count(
    const float* __restrict__ W, uint32_t* __restrict__ ws)
{
    int t  = threadIdx.x;
    int k0 = blockIdx.x * 4;
    int c0 = 0, c1 = 0;
    #pragma unroll
    for (int kk = 0; kk < 4; ++kk) {
        const float* row = W + (size_t)(k0 + kk) * N_NEU;
        c0 += (row[t]       != 0.0f) ? 1 : 0;
        c1 += (row[t + 256] != 0.0f) ? 1 : 0;
    }
    if (c0) atomicAdd(&ws[(WS_CNT >> 2) + t],       (uint32_t)c0);
    if (c1) atomicAdd(&ws[(WS_CNT >> 2) + t + 256], (uint32_t)c1);
}

// ---------------------------------------------------------------- prep B
__global__ __launch_bounds__(512) void lsm_sort(uint32_t* __restrict__ ws)
{
    __shared__ int hist[N_NEU + 1];
    __shared__ int csort[N_NEU];
    __shared__ int gcw[8];

    int t = threadIdx.x;
    int creal = (int)ws[(WS_CNT >> 2) + t];
    for (int i = t; i < N_NEU + 1; i += 512) hist[i] = 0;
    __syncthreads();
    atomicAdd(&hist[creal], 1);
    __syncthreads();
    if (t == 0) {
        int acc = 0;
        for (int v = 0; v <= N_NEU; ++v) { int h = hist[v]; hist[v] = acc; acc += h; }
    }
    __syncthreads();
    int rank = atomicAdd(&hist[creal], 1);
    ws[(WS_PERM >> 2) + rank] = (uint32_t)t;
    ws[(WS_RANK >> 2) + t]    = (uint32_t)rank;
    csort[rank] = creal;
    __syncthreads();
    if (t < 8) {
        int cw = csort[t * 64 + 63];         // ascending -> group max is last
        cw = (cw + 7) & ~7;                  // pad to multiple of 8 (one chunk)
        gcw[t] = cw;
        ws[(WS_CNTW >> 2) + t] = (uint32_t)cw;
    }
    __syncthreads();
    if (t == 0) {
        int ai = 0, aw = 0;
        for (int g = 0; g < 8; ++g) {
            ws[(WS_IBASE >> 2) + g] = (uint32_t)ai;
            ws[(WS_WBASE >> 2) + g] = (uint32_t)aw;
            ai += gcw[g] * 64 * 2;           // bytes (u16 per entry)
            aw += gcw[g] * 64 * 4;           // bytes (f32 per entry)
        }
    }
    __syncthreads();
    // pad tail slots of this thread's column (offset 0 -> neuron 0's record,
    // w=0.0f -> harmless; same-address across lanes -> broadcast, no conflict)
    int wg = rank >> 6, ls = rank & 63;
    int cw = gcw[wg];
    uint32_t ib = ws[(WS_IBASE >> 2) + wg];
    uint32_t wb = ws[(WS_WBASE >> 2) + wg];
    char* base = (char*)ws;
    for (int j = creal; j < cw; ++j) {
        *(unsigned short*)(base + WS_IDX + ib + (j >> 3) * 1024 + ls * 16 + (j & 7) * 2) = 0;
        *(float*)(base + WS_WT + wb + (j >> 3) * 2048 + ls * 32 + (j & 7) * 4) = 0.0f;
    }
}

// ---------------------------------------------------------------- prep C
// One block per COLUMN. Entries written in ROTATED bank-group order:
// bucket r = ((k&7) - (ls&7)) & 7, so at slot j the wave's lanes spread
// uniformly across the 8 bank-groups (b128 per-bank-load equalization).
__global__ __launch_bounds__(64) void lsm_fill(
    const float* __restrict__ W, uint32_t* __restrict__ ws)
{
    int c    = blockIdx.x;
    int lane = threadIdx.x;
    char* base = (char*)ws;
    uint32_t rank = ws[(WS_RANK >> 2) + c];
    int wg = (int)(rank >> 6), ls = (int)(rank & 63);
    uint32_t ib = ws[(WS_IBASE >> 2) + wg];
    uint32_t wb = ws[(WS_WBASE >> 2) + wg];
    int rot = ls & 7;

    __shared__ int bcnt[8];
    __shared__ int bcur[8];
    if (lane < 8) bcnt[lane] = 0;
    __syncthreads();

    // pass 1: count per rotated bucket
    for (int k = lane; k < N_NEU; k += 64) {
        float wv = W[(size_t)k * N_NEU + c];
        if (wv != 0.0f) {
            int r = ((k & 7) - rot) & 7;
            atomicAdd(&bcnt[r], 1);
        }
    }
    __syncthreads();
    if (lane == 0) {
        int acc = 0;
        for (int r = 0; r < 8; ++r) { bcur[r] = acc; acc += bcnt[r]; }
    }
    __syncthreads();

    // pass 2: place entries bucket-by-bucket (order within bucket arbitrary)
    for (int k = lane; k < N_NEU; k += 64) {
        float wv = W[(size_t)k * N_NEU + c];
        if (wv != 0.0f) {
            int r = ((k & 7) - rot) & 7;
            int j = atomicAdd(&bcur[r], 1);
            *(unsigned short*)(base + WS_IDX + ib + (j >> 3) * 1024 + ls * 16 + (j & 7) * 2)
                = (unsigned short)SPK_OFF(k);
            *(float*)(base + WS_WT + wb + (j >> 3) * 2048 + ls * 32 + (j & 7) * 4) = wv;
        }
    }
}

// -------- spill-proof pipeline macros (all scalars, no arrays/fns) --------
// B = spike-buffer base for this step; offsets pre-scaled to 16k.
#define GATH(P, X, B) \
    P##0 = *(const uint4*)((B) + ((X).x & 0xffffu)); \
    P##1 = *(const uint4*)((B) + ((X).x >> 16));     \
    P##2 = *(const uint4*)((B) + ((X).y & 0xffffu)); \
    P##3 = *(const uint4*)((B) + ((X).y >> 16));     \
    P##4 = *(const uint4*)((B) + ((X).z & 0xffffu)); \
    P##5 = *(const uint4*)((B) + ((X).z >> 16));     \
    P##6 = *(const uint4*)((B) + ((X).w & 0xffffu)); \
    P##7 = *(const uint4*)((B) + ((X).w >> 16));

// mixed-precision FMA: acc(f32) += w(f32) * f16 half of S (lo/hi)
#define FMIX_LO(ACC, WV, S) \
    asm("v_fma_mix_f32 %0, %1, %2, %0 op_sel:[0,0,0] op_sel_hi:[0,1,0]" \
        : "+v"(ACC) : "v"(WV), "v"(S));
#define FMIX_HI(ACC, WV, S) \
    asm("v_fma_mix_f32 %0, %1, %2, %0 op_sel:[0,1,0] op_sel_hi:[0,1,0]" \
        : "+v"(ACC) : "v"(WV), "v"(S));

// one entry: weight WV x 8 rows' f16 spikes (uint4 S = 4 f16-pairs)
#define C1(S, WV) \
    FMIX_LO(rec0, WV, (S).x) FMIX_HI(rec1, WV, (S).x) \
    FMIX_LO(rec2, WV, (S).y) FMIX_HI(rec3, WV, (S).y) \
    FMIX_LO(rec4, WV, (S).z) FMIX_HI(rec5, WV, (S).z) \
    FMIX_LO(rec6, WV, (S).w) FMIX_HI(rec7, WV, (S).w)

#define CONS(P, WA, WB) \
    C1(P##0, (WA).x) C1(P##1, (WA).y) C1(P##2, (WA).z) C1(P##3, (WA).w) \
    C1(P##4, (WB).x) C1(P##5, (WB).y) C1(P##6, (WB).z) C1(P##7, (WB).w)

#define LDW(WA, WB, K) \
    WA = ((const float4*)(wp0 + (K) * 2048))[0]; \
    WB = ((const float4*)(wp0 + (K) * 2048))[1];

// ---------------------------------------------------------------- main
// LDS map:
//   [0,8192)       spk buffer 0 (f16 x 8 rows per neuron, 16B @ 16k)
//   [8192,16384)   spk buffer 1 (ping-pong)
//   [16384,32768)  stg: 16KB scratch — state staging / rates rl / out staging
__global__ __launch_bounds__(512, 1)
void lsm_main(
    const float* __restrict__ rates, const float* __restrict__ inW,
    const float* __restrict__ vin,   const float* __restrict__ cin,
    const int* __restrict__ nsteps_p,
    const uint32_t* __restrict__ ws, float* __restrict__ out)
{
    __shared__ __align__(16) unsigned char smem[2 * SPK_BUF + 16384];
    float* stg = (float*)(smem + 2 * SPK_BUF);
    float* rl  = stg;

    int q    = threadIdx.x;
    int blk  = blockIdx.x;
    int r0   = blk * R_PB;
    int w    = q >> 6;
    int lane = q & 63;
    // SIMD balance: waves {s, s+4} share SIMD s; give them groups {s, 7-s}
    int wg   = (w < 4) ? w : (11 - w);
    int n    = (int)ws[(WS_PERM >> 2) + wg * 64 + lane];
    int cw   = (int)ws[(WS_CNTW >> 2) + wg];     // wave-uniform
    int nit  = cw >> 3;                          // 8-entry chunks (<=12)
    const char* ip0 = (const char*)ws + WS_IDX + ws[(WS_IBASE >> 2) + wg]
                    + lane * 16;
    const char* wp0 = (const char*)ws + WS_WT  + ws[(WS_WBASE >> 2) + wg]
                    + lane * 32;
    int spk_n = SPK_OFF(n);                      // this column's record

    // ---- coalesced state staging: cin then vin through LDS ----
    float c0v[R_PB], v0v[R_PB];
    #pragma unroll
    for (int r = 0; r < R_PB; ++r)
        stg[r * N_NEU + q] = cin[(size_t)(r0 + r) * N_NEU + q];   // coalesced
    __syncthreads();
    #pragma unroll
    for (int r = 0; r < R_PB; ++r) c0v[r] = stg[r * N_NEU + n];
    __syncthreads();
    #pragma unroll
    for (int r = 0; r < R_PB; ++r)
        stg[r * N_NEU + q] = vin[(size_t)(r0 + r) * N_NEU + q];   // coalesced
    __syncthreads();
    #pragma unroll
    for (int r = 0; r < R_PB; ++r) v0v[r] = stg[r * N_NEU + n];
    __syncthreads();

    // ---- rates -> rl (coalesced), then I-dot ----
    ((float4*)rl)[q] = ((const float4*)(rates + (size_t)r0 * D_IN))[q];
    __syncthreads();

    float I[R_PB] = {0.f, 0.f, 0.f, 0.f, 0.f, 0.f, 0.f, 0.f};
    {
        const float4* wrow = (const float4*)(inW + (size_t)n * D_IN);
        for (int d4 = 0; d4 < D_IN / 4; ++d4) {
            float4 wv = wrow[d4];
            #pragma unroll
            for (int r = 0; r < R_PB; ++r) {
                const float* rr = rl + r * D_IN + d4 * 4;   // LDS broadcast
                I[r] += wv.x * rr[0] + wv.y * rr[1] + wv.z * rr[2] + wv.w * rr[3];
            }
        }
    }

    // initial f16 spikes -> buffer 0
    uint4 sini = make_uint4(0u, 0u, 0u, 0u);
    #pragma unroll
    for (int r = 0; r < R_PB; ++r) {
        unsigned hb = (c0v[r] > 0.f) ? H16_ONE : 0u;
        unsigned sh = (r & 1) ? 16 : 0;
        if (r < 2)      sini.x |= hb << sh;
        else if (r < 4) sini.y |= hb << sh;
        else if (r < 6) sini.z |= hb << sh;
        else            sini.w |= hb << sh;
    }
    *(uint4*)(smem + spk_n) = sini;

    // packed spike counters: byte r = count of (v>0) for row r (<=64, fits)
    unsigned ssx = 0u, ssy = 0u;

    // preload ENTIRE index stream into registers (constant across steps)
    uint4 xr0, xr1, xr2, xr3, xr4, xr5, xr6, xr7, xr8, xr9, xr10, xr11;
    const uint4 xz = make_uint4(0u, 0u, 0u, 0u);
    xr0  =              *(const uint4*)(ip0);
    xr1  = (1  < nit) ? *(const uint4*)(ip0 + 1024)  : xz;
    xr2  = (2  < nit) ? *(const uint4*)(ip0 + 2048)  : xz;
    xr3  = (3  < nit) ? *(const uint4*)(ip0 + 3072)  : xz;
    xr4  = (4  < nit) ? *(const uint4*)(ip0 + 4096)  : xz;
    xr5  = (5  < nit) ? *(const uint4*)(ip0 + 5120)  : xz;
    xr6  = (6  < nit) ? *(const uint4*)(ip0 + 6144)  : xz;
    xr7  = (7  < nit) ? *(const uint4*)(ip0 + 7168)  : xz;
    xr8  = (8  < nit) ? *(const uint4*)(ip0 + 8192)  : xz;
    xr9  = (9  < nit) ? *(const uint4*)(ip0 + 9216)  : xz;
    xr10 = (10 < nit) ? *(const uint4*)(ip0 + 10240) : xz;
    xr11 = (11 < nit) ? *(const uint4*)(ip0 + 11264) : xz;

    const float AS   = (float)0.8187307530779818;   // exp(-1/5)
    const float OMAS = (float)(1.0 - 0.8187307530779818);
    const float AM   = (float)0.9512294245007140;   // exp(-1/20)
    const float OMAM = (float)(1.0 - 0.9512294245007140);

    int T = nsteps_p[0];
    __syncthreads();   // initial spikes visible

    #pragma unroll 1
    for (int t = 0; t < T; ++t) {
        const unsigned char* sb = smem + ((t & 1) ? SPK_BUF : 0);   // read buf
        unsigned char*       db = smem + ((t & 1) ? 0 : SPK_BUF);   // write buf

        float rec0 = 0.f, rec1 = 0.f, rec2 = 0.f, rec3 = 0.f;
        float rec4 = 0.f, rec5 = 0.f, rec6 = 0.f, rec7 = 0.f;
        uint4 a0, a1, a2, a3, a4, a5, a6, a7;
        uint4 b0, b1, b2, b3, b4, b5, b6, b7;
        float4 waA, wbA, waB, wbB;

        // 2-deep pipeline: gather addrs from registers, weights 2-deep.
        LDW(waA, wbA, 0)
        GATH(a, xr0, sb)
        if (1 < nit)  { LDW(waB, wbB, 1)  GATH(b, xr1, sb)  }
        CONS(a, waA, wbA)
        if (1 < nit)  {
            if (2 < nit)  { LDW(waA, wbA, 2)  GATH(a, xr2, sb)  }
            CONS(b, waB, wbB)
        }
        if (2 < nit)  {
            if (3 < nit)  { LDW(waB, wbB, 3)  GATH(b, xr3, sb)  }
            CONS(a, waA, wbA)
        }
        if (3 < nit)  {
            if (4 < nit)  { LDW(waA, wbA, 4)  GATH(a, xr4, sb)  }
            CONS(b, waB, wbB)
        }
        if (4 < nit)  {
            if (5 < nit)  { LDW(waB, wbB, 5)  GATH(b, xr5, sb)  }
            CONS(a, waA, wbA)
        }
        if (5 < nit)  {
            if (6 < nit)  { LDW(waA, wbA, 6)  GATH(a, xr6, sb)  }
            CONS(b, waB, wbB)
        }
        if (6 < nit)  {
            if (7 < nit)  { LDW(waB, wbB, 7)  GATH(b, xr7, sb)  }
            CONS(a, waA, wbA)
        }
        if (7 < nit)  {
            if (8 < nit)  { LDW(waA, wbA, 8)  GATH(a, xr8, sb)  }
            CONS(b, waB, wbB)
        }
        if (8 < nit)  {
            if (9 < nit)  { LDW(waB, wbB, 9)  GATH(b, xr9, sb)  }
            CONS(a, waA, wbA)
        }
        if (9 < nit)  {
            if (10 < nit) { LDW(waA, wbA, 10) GATH(a, xr10, sb) }
            CONS(b, waB, wbB)
        }
        if (10 < nit) {
            if (11 < nit) { LDW(waB, wbB, 11) GATH(b, xr11, sb) }
            CONS(a, waA, wbA)
        }
        if (11 < nit) {
            CONS(b, waB, wbB)
        }

        // update; write new f16 spikes to the other buffer (no WAR hazard)
        uint4 ns = make_uint4(0u, 0u, 0u, 0u);
        unsigned vbx = 0u, vby = 0u;
        {
            float rca[R_PB] = {rec0, rec1, rec2, rec3, rec4, rec5, rec6, rec7};
            #pragma unroll
            for (int r = 0; r < R_PB; ++r) {
                c0v[r] = AS * c0v[r] + OMAS * (I[r] + rca[r]);
                v0v[r] = AM * v0v[r] + OMAM * c0v[r];
                unsigned hb = (c0v[r] > 0.f) ? H16_ONE : 0u;
                unsigned vb = (v0v[r] > 0.f) ? 1u : 0u;
                unsigned sh = (r & 1) ? 16 : 0;
                if (r < 2)      ns.x |= hb << sh;
                else if (r < 4) ns.y |= hb << sh;
                else if (r < 6) ns.z |= hb << sh;
                else            ns.w |= hb << sh;
                if (r < 4) vbx |= vb << (r * 8);
                else       vby |= vb << ((r - 4) * 8);
            }
        }
        ssx += vbx;   // bytewise counters, max 64 < 256: no inter-byte carry
        ssy += vby;
        *(uint4*)(db + spk_n) = ns;
        __syncthreads();   // new spikes visible; old buffer free for reuse
    }

    // ---- coalesced epilogue: stage each quantity through LDS ----
    float invT = 1.0f / (float)T;
    size_t BN = (size_t)B_ROWS * N_NEU;

    #pragma unroll
    for (int r = 0; r < R_PB; ++r) {
        unsigned cnt = (r < 4) ? ((ssx >> (r * 8)) & 0xffu)
                               : ((ssy >> ((r - 4) * 8)) & 0xffu);
        stg[r * N_NEU + n] = (float)cnt * invT;
    }
    __syncthreads();
    #pragma unroll
    for (int r = 0; r < R_PB; ++r)
        out[(size_t)(r0 + r) * N_NEU + q] = stg[r * N_NEU + q];   // coalesced
    __syncthreads();

    #pragma unroll
    for (int r = 0; r < R_PB; ++r) stg[r * N_NEU + n] = v0v[r];
    __syncthreads();
    #pragma unroll
    for (int r = 0; r < R_PB; ++r)
        out[BN + (size_t)(r0 + r) * N_NEU + q] = stg[r * N_NEU + q];
    __syncthreads();

    #pragma unroll
    for (int r = 0; r < R_PB; ++r) stg[r * N_NEU + n] = c0v[r];
    __syncthreads();
    #pragma unroll
    for (int r = 0; r < R_PB; ++r)
        out[2 * BN + (size_t)(r0 + r) * N_NEU + q] = stg[r * N_NEU + q];
}

// ---------------------------------------------------------------- launch
extern "C" void kernel_launch(void* const* d_in, const int* in_sizes, int n_in,
                              void* d_out, int out_size, void* d_ws, size_t ws_size,
                              hipStream_t stream)
{
    const float* rates = (const float*)d_in[0];
    const float* inW   = (const float*)d_in[1];
    const float* W     = (const float*)d_in[2];
    const float* vin   = (const float*)d_in[3];
    const float* cin   = (const float*)d_in[4];
    const int*   nst   = (const int*)d_in[5];
    uint32_t* ws = (uint32_t*)d_ws;
    float* out = (float*)d_out;
    (void)in_sizes; (void)n_in; (void)out_size; (void)ws_size;

    // zero CNT (harness poisons d_ws to 0xAA before every call)
    hipMemsetAsync((char*)d_ws + WS_CNT, 0, 2048, stream);

    lsm_count<<<128, 256, 0, stream>>>(W, ws);
    lsm_sort<<<1, 512, 0, stream>>>(ws);
    lsm_fill<<<N_NEU, 64, 0, stream>>>(W, ws);
    lsm_main<<<NBLK, 512, 0, stream>>>(rates, inW, vin, cin, nst, ws, out);
}